// Round 3
// baseline (150.400 us; speedup 1.0000x reference)
//
#include <hip/hip_runtime.h>
#include <hip/hip_bf16.h>

// Problem constants
#define Bk 8
#define Nk 10000
#define Ek 160000
#define Hk 128
#define Zk 64
#define NPk 10112   // 79*128, per-batch padded row count
#define CAPk 64     // bucket-CSR capacity; deg ~ Poisson(16), P(deg>=64) < 1e-17

typedef float f32x4 __attribute__((ext_vector_type(4)));
typedef short s16x8 __attribute__((ext_vector_type(8)));

// init: pack WBT (128x256 bf16: [W2l | W2r] rows), zero cur + pooled
__global__ __launch_bounds__(256) void k0_init(const float* __restrict__ W2l, const float* __restrict__ W2r,
                                               __hip_bfloat16* __restrict__ wbt, int* __restrict__ cur,
                                               float* __restrict__ pooled){
  int t = blockIdx.x*256 + threadIdx.x;
  if (t < 128*256){
    int o = t >> 8, k = t & 255;
    float v = (k < 128) ? W2l[o*128+k] : W2r[o*128+(k-128)];
    wbt[t] = __float2bfloat16(v);
  }
  if (t < Nk) cur[t] = 0;
  if (t < Bk*Hk) pooled[t] = 0.f;
}

// bucket-CSR fill: csrsrc[d*CAP + p] = src, cur[d] = degree
__global__ void k3_fill(const int* __restrict__ ei, int* __restrict__ cur, int* __restrict__ csrsrc){
  int e = blockIdx.x*blockDim.x + threadIdx.x;
  if (e < Ek){
    int s = ei[e], d = ei[Ek+e];
    int p = atomicAdd(&cur[d], 1);
    if (p < CAPk) csrsrc[d*CAPk + p] = s;
  }
}

// agg1[b,i] = mean over incoming edges of x[b,src]
__global__ void k4_agg1(const float* __restrict__ x, const int* __restrict__ cur,
                        const int* __restrict__ csrsrc, float* __restrict__ agg1){
  int i = blockIdx.x*blockDim.x + threadIdx.x;
  int b = blockIdx.y;
  if (i >= Nk) return;
  int degc = cur[i];
  int deg = min(degc, CAPk);
  const float* xb = x + b*Nk;
  const int* col = csrsrc + i*CAPk;
  float sum=0.f;
  for (int k=0;k<deg;k++) sum += xb[col[k]];
  agg1[b*Nk+i] = sum / fmaxf((float)degc, 1.f);
}

// XMAT[b*NP+i][0:128]=AGG2, [128:256]=H1 (bf16). Block per node, 128 threads = h.
// All per-edge data (j, agg1[b][j], x[b][j]) is wave-uniform -> scalar loads on
// the SALU/K$ pipe; VALU does only 4 ops per (edge,batch). No LDS, no barriers.
__global__ __launch_bounds__(128) void k5_xmat(const float* __restrict__ x, const float* __restrict__ agg1,
                        const int* __restrict__ cur, const int* __restrict__ csrsrc,
                        const float* __restrict__ W1l, const float* __restrict__ b1,
                        const float* __restrict__ W1r,
                        __hip_bfloat16* __restrict__ xmat){
  int i = blockIdx.x, t = threadIdx.x;
  if (i >= Nk){
    #pragma unroll
    for (int b=0;b<Bk;b++){
      __hip_bfloat16* o = xmat + ((size_t)b*NPk + i)*256;
      o[t]     = __float2bfloat16(0.f);
      o[128+t] = __float2bfloat16(0.f);
    }
    return;
  }
  float w1l=W1l[t], w1r=W1r[t], bb=b1[t];
  int degc = cur[i];
  int deg = min(degc, CAPk);
  const int* col = csrsrc + i*CAPk;
  float acc[Bk];
  #pragma unroll
  for (int b=0;b<Bk;b++) acc[b]=0.f;

  #pragma unroll 2
  for (int k=0;k<deg;++k){
    int j = __builtin_amdgcn_readfirstlane(col[k]);
    #pragma unroll
    for (int b=0;b<Bk;b++){
      float a  = agg1[b*Nk+j];
      float xx = x[b*Nk+j];
      acc[b] += fmaxf(fmaf(a, w1l, fmaf(xx, w1r, bb)), 0.f);
    }
  }

  float inv = 1.f/fmaxf((float)degc, 1.f);
  #pragma unroll
  for (int b=0;b<Bk;b++){
    float a_i = agg1[b*Nk+i], x_i = x[b*Nk+i];
    float h1 = fmaxf(fmaf(a_i, w1l, fmaf(x_i, w1r, bb)), 0.f);
    __hip_bfloat16* o = xmat + ((size_t)b*NPk + i)*256;
    o[t]     = __float2bfloat16(acc[b]*inv);
    o[128+t] = __float2bfloat16(h1);
  }
}

__device__ inline void mfma_bf16(f32x4& d, s16x8 a, s16x8 b){
  asm("v_mfma_f32_16x16x32_bf16 %0, %1, %2, %0" : "+v"(d) : "v"(a), "v"(b));
}

// GEMM (NPk rows x 256) @ WBT^T (256 x 128), relu+bias, column-sum into pooled (atomic).
__global__ __launch_bounds__(256) void k6_gemm(const __hip_bfloat16* __restrict__ xmat,
                                               const __hip_bfloat16* __restrict__ wbt,
                                               const float* __restrict__ b2, float* __restrict__ pooled){
  int wid = threadIdx.x >> 6, lane = threadIdx.x & 63;
  int b = blockIdx.y;
  int row0 = blockIdx.x*128 + wid*32;       // within NPk
  int lr = lane & 15, lk = lane >> 4;
  const __hip_bfloat16* xbase = xmat + ((size_t)b*NPk + row0)*256;

  f32x4 acc[2][8];
  #pragma unroll
  for (int mf=0; mf<2; ++mf)
    #pragma unroll
    for (int nf=0; nf<8; ++nf) acc[mf][nf] = (f32x4){0.f,0.f,0.f,0.f};

  for (int kk=0; kk<8; ++kk){
    int ko = kk*32 + lk*8;
    s16x8 a0 = *(const s16x8*)(const void*)(xbase + lr*256 + ko);
    s16x8 a1 = *(const s16x8*)(const void*)(xbase + (16+lr)*256 + ko);
    #pragma unroll
    for (int nf=0; nf<8; ++nf){
      s16x8 bfr = *(const s16x8*)(const void*)(wbt + (nf*16+lr)*256 + ko);
      mfma_bf16(acc[0][nf], a0, bfr);
      mfma_bf16(acc[1][nf], a1, bfr);
    }
  }

  // epilogue: relu(acc + b2), mask pad rows, column-reduce, atomic into pooled
  #pragma unroll
  for (int nf=0; nf<8; ++nf){
    int col = nf*16 + lr;
    float bias = b2[col];
    float v = 0.f;
    #pragma unroll
    for (int mf=0; mf<2; ++mf){
      int rbase = row0 + mf*16 + lk*4;
      #pragma unroll
      for (int r=0;r<4;++r){
        float val = fmaxf(acc[mf][nf][r] + bias, 0.f);
        if (rbase + r < Nk) v += val;
      }
    }
    v += __shfl_xor(v, 16);
    v += __shfl_xor(v, 32);
    if (lane < 16) atomicAdd(&pooled[b*Hk + col], v);
  }
}

__global__ void k7_final(const float* __restrict__ pooled, const float* __restrict__ Wro1,
                         const float* __restrict__ bro1, const float* __restrict__ Wro2,
                         const float* __restrict__ bro2, float* __restrict__ out){
  int b = blockIdx.x, t = threadIdx.x;
  __shared__ float pool[128];
  __shared__ float hid[128];
  pool[t] = pooled[b*Hk + t] * (1.0f/(float)Nk);
  __syncthreads();
  float s = bro1[t];
  for (int d=0; d<128; ++d) s += Wro1[t*128+d]*pool[d];
  hid[t] = fmaxf(s, 0.f);
  __syncthreads();
  if (t < Zk){
    float s2 = bro2[t];
    for (int d=0; d<128; ++d) s2 += Wro2[t*128+d]*hid[d];
    out[b*Zk + t] = s2;
  }
}

extern "C" void kernel_launch(void* const* d_in, const int* in_sizes, int n_in,
                              void* d_out, int out_size, void* d_ws, size_t ws_size,
                              hipStream_t stream) {
  const float* x    = (const float*)d_in[0];
  const int*   ei   = (const int*)d_in[1];
  const float* W1l  = (const float*)d_in[2];
  const float* b1   = (const float*)d_in[3];
  const float* W1r  = (const float*)d_in[4];
  const float* W2l  = (const float*)d_in[5];
  const float* b2   = (const float*)d_in[6];
  const float* W2r  = (const float*)d_in[7];
  const float* Wro1 = (const float*)d_in[8];
  const float* bro1 = (const float*)d_in[9];
  const float* Wro2 = (const float*)d_in[10];
  const float* bro2 = (const float*)d_in[11];
  float* out = (float*)d_out;

  // workspace layout (bytes, 256-aligned)
  char* ws = (char*)d_ws;
  int*   cur    = (int*)(ws + 0);              // 40000
  float* pooled = (float*)(ws + 40448);        // 4096
  __hip_bfloat16* wbt  = (__hip_bfloat16*)(ws + 44544);   // 65536
  int*   csrsrc = (int*)(ws + 110080);         // 10000*64*4 = 2560000
  float* agg1   = (float*)(ws + 2670080);      // 320000
  __hip_bfloat16* xmat = (__hip_bfloat16*)(ws + 2990336); // 8*10112*256*2 = 41418752

  k0_init<<<dim3(128), 256, 0, stream>>>(W2l, W2r, wbt, cur, pooled);
  k3_fill<<<dim3((Ek+255)/256), 256, 0, stream>>>(ei, cur, csrsrc);
  k4_agg1<<<dim3((Nk+255)/256, Bk), 256, 0, stream>>>(x, cur, csrsrc, agg1);
  k5_xmat<<<dim3(NPk), 128, 0, stream>>>(x, agg1, cur, csrsrc, W1l, b1, W1r, xmat);
  k6_gemm<<<dim3(NPk/128, Bk), 256, 0, stream>>>(xmat, wbt, b2, pooled);
  k7_final<<<dim3(Bk), 128, 0, stream>>>(pooled, Wro1, bro1, Wro2, bro2, out);
}

// Round 5
// 114.236 us; speedup vs baseline: 1.3166x; 1.3166x over previous
//
#include <hip/hip_runtime.h>
#include <hip/hip_bf16.h>

// Problem constants
#define Bk 8
#define Nk 10000
#define Ek 160000
#define Hk 128
#define Zk 64
#define NPk 10112   // 79*128, per-batch padded row count
#define CAPk 64     // bucket-CSR capacity; deg ~ Poisson(16), P(deg>=64) ~ 0

typedef float f32x4 __attribute__((ext_vector_type(4)));
typedef float f32x2 __attribute__((ext_vector_type(2)));
typedef short s16x8 __attribute__((ext_vector_type(8)));

__device__ inline f32x2 pk_fma(f32x2 a, f32x2 b, f32x2 c){
  f32x2 d; asm("v_pk_fma_f32 %0, %1, %2, %3" : "=v"(d) : "v"(a), "v"(b), "v"(c)); return d;
}
// no v_pk_max_f32 on gfx950 -> two scalar v_max_f32
__device__ inline f32x2 pk_max0(f32x2 a){
  f32x2 d; d.x = fmaxf(a.x, 0.f); d.y = fmaxf(a.y, 0.f); return d;
}
__device__ inline f32x2 pk_add(f32x2 a, f32x2 b){
  f32x2 d; asm("v_pk_add_f32 %0, %1, %2" : "=v"(d) : "v"(a), "v"(b)); return d;
}

// init: pack WBT (128x256 bf16: [W2l | W2r] rows), zero cur + pooled
__global__ __launch_bounds__(256) void k0_init(const float* __restrict__ W2l, const float* __restrict__ W2r,
                                               __hip_bfloat16* __restrict__ wbt, int* __restrict__ cur,
                                               float* __restrict__ pooled){
  int t = blockIdx.x*256 + threadIdx.x;
  if (t < 128*256){
    int o = t >> 8, k = t & 255;
    float v = (k < 128) ? W2l[o*128+k] : W2r[o*128+(k-128)];
    wbt[t] = __float2bfloat16(v);
  }
  if (t < Nk) cur[t] = 0;
  if (t < Bk*Hk) pooled[t] = 0.f;
}

// bucket-CSR fill: csrsrc[d*CAP + p] = src, cur[d] = degree
__global__ void k3_fill(const int* __restrict__ ei, int* __restrict__ cur, int* __restrict__ csrsrc){
  int e = blockIdx.x*blockDim.x + threadIdx.x;
  if (e < Ek){
    int s = ei[e], d = ei[Ek+e];
    int p = atomicAdd(&cur[d], 1);
    if (p < CAPk) csrsrc[d*CAPk + p] = s;
  }
}

// agg1[b,i] = mean over incoming edges of x[b,src]
__global__ void k4_agg1(const float* __restrict__ x, const int* __restrict__ cur,
                        const int* __restrict__ csrsrc, float* __restrict__ agg1){
  int i = blockIdx.x*blockDim.x + threadIdx.x;
  int b = blockIdx.y;
  if (i >= Nk) return;
  int degc = cur[i];
  int deg = min(degc, CAPk);
  const float* xb = x + b*Nk;
  const int* col = csrsrc + i*CAPk;
  float sum=0.f;
  for (int k=0;k<deg;k++) sum += xb[col[k]];
  agg1[b*Nk+i] = sum / fmaxf((float)degc, 1.f);
}

// XMAT[b*NP+i][0:128]=AGG2, [128:256]=H1 (bf16). Block per node, 128 threads = h.
// Phase 1 (parallel gather): 128 threads cover 64 edge-slots x 8 batches in 4
// steps, landing (agg1_j, x_j) in SoA LDS; slots >= deg are zeroed.
// Phase 2 (packed compute): thread = h; b128 broadcast reads of 4 edges, packed
// v_pk_fma / scalar max / v_pk_add -> 2.5 VALU inst per (edge,batch). Pad slots
// contribute relu(b1) each, subtracted analytically.
__global__ __launch_bounds__(128) void k5_xmat(const float* __restrict__ x, const float* __restrict__ agg1,
                        const int* __restrict__ cur, const int* __restrict__ csrsrc,
                        const float* __restrict__ W1l, const float* __restrict__ b1,
                        const float* __restrict__ W1r,
                        __hip_bfloat16* __restrict__ xmat){
  int i = blockIdx.x, t = threadIdx.x;
  if (i >= Nk){
    #pragma unroll
    for (int b=0;b<Bk;b++){
      __hip_bfloat16* o = xmat + ((size_t)b*NPk + i)*256;
      o[t]     = __float2bfloat16(0.f);
      o[128+t] = __float2bfloat16(0.f);
    }
    return;
  }
  __shared__ float sA[Bk][CAPk];
  __shared__ float sX[Bk][CAPk];

  int degc = cur[i];
  int deg = min(degc, CAPk);
  float w1l=W1l[t], w1r=W1r[t], bb=b1[t];

  // gather phase: k = t&63, half = t>>6; batches {2q+half}
  int k = t & 63, half = t >> 6;
  bool valid = (k < deg);
  int j = valid ? csrsrc[i*CAPk + k] : 0;
  #pragma unroll
  for (int q=0;q<4;q++){
    int b = 2*q + half;
    float a = 0.f, xx = 0.f;
    if (valid){ a = agg1[b*Nk+j]; xx = x[b*Nk+j]; }
    sA[b][k] = a; sX[b][k] = xx;
  }
  __syncthreads();

  int deg4 = (deg + 3) & ~3;
  float relu_bb = fmaxf(bb, 0.f);
  float npad = (float)(deg4 - deg);
  float inv = 1.f/fmaxf((float)degc, 1.f);
  f32x2 w1l2 = {w1l,w1l}, w1r2 = {w1r,w1r}, bb2 = {bb,bb};

  #pragma unroll
  for (int b=0;b<Bk;b++){
    f32x2 acc2 = {0.f,0.f};
    const f32x4* rA = (const f32x4*)&sA[b][0];
    const f32x4* rX = (const f32x4*)&sX[b][0];
    for (int k4=0; k4<deg4; k4+=4){
      f32x4 av = rA[k4>>2];
      f32x4 xv = rX[k4>>2];
      f32x2 alo = __builtin_shufflevector(av,av,0,1);
      f32x2 ahi = __builtin_shufflevector(av,av,2,3);
      f32x2 xlo = __builtin_shufflevector(xv,xv,0,1);
      f32x2 xhi = __builtin_shufflevector(xv,xv,2,3);
      f32x2 p = pk_fma(xlo,w1r2,bb2); p = pk_fma(alo,w1l2,p); p = pk_max0(p); acc2 = pk_add(acc2,p);
      f32x2 q2 = pk_fma(xhi,w1r2,bb2); q2 = pk_fma(ahi,w1l2,q2); q2 = pk_max0(q2); acc2 = pk_add(acc2,q2);
    }
    float accs = acc2.x + acc2.y - npad*relu_bb;
    float a_i = agg1[b*Nk+i], x_i = x[b*Nk+i];
    float h1 = fmaxf(fmaf(a_i,w1l,fmaf(x_i,w1r,bb)), 0.f);
    __hip_bfloat16* o = xmat + ((size_t)b*NPk + i)*256;
    o[t]     = __float2bfloat16(accs*inv);
    o[128+t] = __float2bfloat16(h1);
  }
}

__device__ inline void mfma_bf16(f32x4& d, s16x8 a, s16x8 b){
  asm("v_mfma_f32_16x16x32_bf16 %0, %1, %2, %0" : "+v"(d) : "v"(a), "v"(b));
}

// GEMM (NPk rows x 256) @ WBT^T (256 x 128), relu+bias, column-sum into pooled (atomic).
__global__ __launch_bounds__(256) void k6_gemm(const __hip_bfloat16* __restrict__ xmat,
                                               const __hip_bfloat16* __restrict__ wbt,
                                               const float* __restrict__ b2, float* __restrict__ pooled){
  int wid = threadIdx.x >> 6, lane = threadIdx.x & 63;
  int b = blockIdx.y;
  int row0 = blockIdx.x*128 + wid*32;       // within NPk
  int lr = lane & 15, lk = lane >> 4;
  const __hip_bfloat16* xbase = xmat + ((size_t)b*NPk + row0)*256;

  f32x4 acc[2][8];
  #pragma unroll
  for (int mf=0; mf<2; ++mf)
    #pragma unroll
    for (int nf=0; nf<8; ++nf) acc[mf][nf] = (f32x4){0.f,0.f,0.f,0.f};

  for (int kk=0; kk<8; ++kk){
    int ko = kk*32 + lk*8;
    s16x8 a0 = *(const s16x8*)(const void*)(xbase + lr*256 + ko);
    s16x8 a1 = *(const s16x8*)(const void*)(xbase + (16+lr)*256 + ko);
    #pragma unroll
    for (int nf=0; nf<8; ++nf){
      s16x8 bfr = *(const s16x8*)(const void*)(wbt + (nf*16+lr)*256 + ko);
      mfma_bf16(acc[0][nf], a0, bfr);
      mfma_bf16(acc[1][nf], a1, bfr);
    }
  }

  // epilogue: relu(acc + b2), mask pad rows, column-reduce, atomic into pooled
  #pragma unroll
  for (int nf=0; nf<8; ++nf){
    int col = nf*16 + lr;
    float bias = b2[col];
    float v = 0.f;
    #pragma unroll
    for (int mf=0; mf<2; ++mf){
      int rbase = row0 + mf*16 + lk*4;
      #pragma unroll
      for (int r=0;r<4;++r){
        float val = fmaxf(acc[mf][nf][r] + bias, 0.f);
        if (rbase + r < Nk) v += val;
      }
    }
    v += __shfl_xor(v, 16);
    v += __shfl_xor(v, 32);
    if (lane < 16) atomicAdd(&pooled[b*Hk + col], v);
  }
}

__global__ void k7_final(const float* __restrict__ pooled, const float* __restrict__ Wro1,
                         const float* __restrict__ bro1, const float* __restrict__ Wro2,
                         const float* __restrict__ bro2, float* __restrict__ out){
  int b = blockIdx.x, t = threadIdx.x;
  __shared__ float pool[128];
  __shared__ float hid[128];
  pool[t] = pooled[b*Hk + t] * (1.0f/(float)Nk);
  __syncthreads();
  float s = bro1[t];
  for (int d=0; d<128; ++d) s += Wro1[t*128+d]*pool[d];
  hid[t] = fmaxf(s, 0.f);
  __syncthreads();
  if (t < Zk){
    float s2 = bro2[t];
    for (int d=0; d<128; ++d) s2 += Wro2[t*128+d]*hid[d];
    out[b*Zk + t] = s2;
  }
}

extern "C" void kernel_launch(void* const* d_in, const int* in_sizes, int n_in,
                              void* d_out, int out_size, void* d_ws, size_t ws_size,
                              hipStream_t stream) {
  const float* x    = (const float*)d_in[0];
  const int*   ei   = (const int*)d_in[1];
  const float* W1l  = (const float*)d_in[2];
  const float* b1   = (const float*)d_in[3];
  const float* W1r  = (const float*)d_in[4];
  const float* W2l  = (const float*)d_in[5];
  const float* b2   = (const float*)d_in[6];
  const float* W2r  = (const float*)d_in[7];
  const float* Wro1 = (const float*)d_in[8];
  const float* bro1 = (const float*)d_in[9];
  const float* Wro2 = (const float*)d_in[10];
  const float* bro2 = (const float*)d_in[11];
  float* out = (float*)d_out;

  // workspace layout (bytes, 256-aligned)
  char* ws = (char*)d_ws;
  int*   cur    = (int*)(ws + 0);              // 40000
  float* pooled = (float*)(ws + 40448);        // 4096
  __hip_bfloat16* wbt  = (__hip_bfloat16*)(ws + 44544);   // 65536
  int*   csrsrc = (int*)(ws + 110080);         // 10000*64*4 = 2560000
  float* agg1   = (float*)(ws + 2670080);      // 320000
  __hip_bfloat16* xmat = (__hip_bfloat16*)(ws + 2990336); // 8*10112*256*2 = 41418752

  k0_init<<<dim3(128), 256, 0, stream>>>(W2l, W2r, wbt, cur, pooled);
  k3_fill<<<dim3((Ek+255)/256), 256, 0, stream>>>(ei, cur, csrsrc);
  k4_agg1<<<dim3((Nk+255)/256, Bk), 256, 0, stream>>>(x, cur, csrsrc, agg1);
  k5_xmat<<<dim3(NPk), 128, 0, stream>>>(x, agg1, cur, csrsrc, W1l, b1, W1r, xmat);
  k6_gemm<<<dim3(NPk/128, Bk), 256, 0, stream>>>(xmat, wbt, b2, pooled);
  k7_final<<<dim3(Bk), 128, 0, stream>>>(pooled, Wro1, bro1, Wro2, bro2, out);
}